// Round 4
// baseline (481.382 us; speedup 1.0000x reference)
//
#include <hip/hip_runtime.h>
#include <hip/hip_bf16.h>

#define HID 256
#define NROWS 2048
#define GRID (NROWS / 8)        // 256 blocks, 8 waves each, 1 wave = 1 n-row

typedef __attribute__((ext_vector_type(8))) short short8;   // 8 bf16 (MFMA A/B frag)
typedef __attribute__((ext_vector_type(4))) float float4v;
typedef __attribute__((ext_vector_type(4))) unsigned int uint4v;

__device__ __forceinline__ unsigned int pk_bf16(float a, float b) {
    __hip_bfloat162 p = __float22bfloat162_rn(float2{a, b});  // v_cvt_pk_bf16_f32
    return *(unsigned int*)&p;
}

// sum across each 16-lane DPP row (VALU pipe, no LDS)
__device__ __forceinline__ float row16_sum(float v) {
    float t;
    t = __builtin_bit_cast(float, __builtin_amdgcn_update_dpp(
            0, __builtin_bit_cast(int, v), 0xB1, 0xf, 0xf, true));  // quad_perm(1,0,3,2)
    v += t;
    t = __builtin_bit_cast(float, __builtin_amdgcn_update_dpp(
            0, __builtin_bit_cast(int, v), 0x4E, 0xf, 0xf, true));  // quad_perm(2,3,0,1)
    v += t;
    t = __builtin_bit_cast(float, __builtin_amdgcn_update_dpp(
            0, __builtin_bit_cast(int, v), 0x124, 0xf, 0xf, true)); // row_ror:4
    v += t;
    t = __builtin_bit_cast(float, __builtin_amdgcn_update_dpp(
            0, __builtin_bit_cast(int, v), 0x128, 0xf, 0xf, true)); // row_ror:8
    v += t;
    return v;
}

// Wave-independent design: W (bf16, XOR-swizzled, 128 KB) lives in LDS and is
// shared read-only by all 8 waves. Each wave owns ONE n-row end-to-end: the
// softmax denominator is wave-local (DPP row sums), so the main loop has ZERO
// barriers. x for the final multiply is recovered in accumulator layout via an
// identity-MFMA (no LDS staging of x at all).
// R3 bugfix: swizzle XOR must act on the FULL within-row k-offset on BOTH
// sides (read previously XORed before adding kt*64 -> bit-6 carry corrupted
// odd-kt reads for c&4 lanes). swzbase[kt] now precomputed correctly.
__global__ __launch_bounds__(512, 2) void attend_fused(
    const float* __restrict__ x, const float* __restrict__ W,
    const float* __restrict__ bias, const float* __restrict__ ctx,
    float* __restrict__ out)
{
    __shared__ unsigned short Wb[256 * 256];   // 128 KB, [col][k] bf16, swizzled

    const int tid  = threadIdx.x;
    const int wave = tid >> 6;    // 0..7
    const int lane = tid & 63;
    const int q    = lane >> 4;   // quad 0..3
    const int c    = lane & 15;
    const int n    = blockIdx.x * 8 + wave;
    const float* xn = x + (size_t)n * (64 * 256);

    // ---- issue chunk-0 x loads first: HBM stream starts under W staging ----
    // A-frag layout: lane (c,q) holds x[word c][k = kt*32 + q*8 + j]
    float4v xa[8], xb[8];
    {
        const float* xr = xn + c * 256 + q * 8;
#pragma unroll
        for (int kt = 0; kt < 8; ++kt) {
            xa[kt] = *(const float4v*)(xr + kt * 32);
            xb[kt] = *(const float4v*)(xr + kt * 32 + 4);
        }
    }

    // ---- stage W (f32 -> bf16) into swizzled LDS; W is L3-resident ----
    {
        char* wbb = (char*)Wb;
#pragma unroll 4
        for (int i = 0; i < 32; ++i) {
            const int f4  = tid + 512 * i;        // 0..16383 float4 chunks
            const int col = f4 >> 6;              // W output-col (0..255)
            const int k4  = (f4 & 63) * 4;        // k position (floats)
            float4v v = *((const float4v*)W + f4);
            uint2 u;
            u.x = pk_bf16(v.x, v.y);
            u.y = pk_bf16(v.z, v.w);
            const int byte = (col * 512 + k4 * 2) ^ ((col & 7) << 4);  // T2 swizzle
            *(uint2*)(wbb + byte) = u;
        }
    }

    // ---- per-lane epilogue constants: hid col = nt*16 + c ----
    // e^(ctx*tanh(y)) = 2^(f*(1 - 2/(E+1))),  f = ctx*log2e,  E = 2^(2y*log2e)
    float bias16[16], f216[16];
#pragma unroll
    for (int nt = 0; nt < 16; ++nt) {
        const int o = nt * 16 + c;
        bias16[nt] = bias[o];
        f216[nt]  = ctx[o] * 1.4426950408889634f;
    }

    // ---- identity B-fragments: mfma(xfrag[kt'], ifr[p]) = x in D-layout ----
    // I[k][col] = 1 iff k == p*16 + col ; lane holds B[k=q*8+j][col=c]
    short8 ifr[2];
#pragma unroll
    for (int p = 0; p < 2; ++p) {
        short8 f = (short8){0, 0, 0, 0, 0, 0, 0, 0};
#pragma unroll
        for (int j = 0; j < 8; ++j)
            f[j] = (q * 8 + j == p * 16 + c) ? (short)0x3F80 : (short)0;
        ifr[p] = f;
    }

    // ---- loop-invariant swizzled read bases: XOR over FULL k-offset ----
    int swzbase[8];
#pragma unroll
    for (int kt = 0; kt < 8; ++kt)
        swzbase[kt] = c * 512 + ((kt * 64 + q * 16) ^ ((c & 7) << 4));

    __syncthreads();   // the ONLY block barrier: Wb ready

    const char* wbb = (const char*)Wb;

    float oacc[16];
#pragma unroll
    for (int nt = 0; nt < 16; ++nt) oacc[nt] = 0.f;

#pragma unroll 1
    for (int ch = 0; ch < 4; ++ch) {   // 4 chunks x 16 words = 64 words
        // ---- cvt staged f32 -> bf16 A-frags (vmcnt wait for chunk ch lands here)
        short8 xfrag[8];
#pragma unroll
        for (int kt = 0; kt < 8; ++kt) {
            uint4v u = { pk_bf16(xa[kt].x, xa[kt].y), pk_bf16(xa[kt].z, xa[kt].w),
                         pk_bf16(xb[kt].x, xb[kt].y), pk_bf16(xb[kt].z, xb[kt].w) };
            xfrag[kt] = __builtin_bit_cast(short8, u);
        }
        // ---- prefetch next chunk: in flight across GEMM+epilogue+final ----
        if (ch < 3) {
            const float* xr = xn + ((ch + 1) * 16 + c) * 256 + q * 8;
#pragma unroll
            for (int kt = 0; kt < 8; ++kt) {
                xa[kt] = *(const float4v*)(xr + kt * 32);
                xb[kt] = *(const float4v*)(xr + kt * 32 + 4);
            }
        }

        // ---- GEMM: 16 words x 256 cols, B from swizzled LDS ----
        float4v acc[16];
#pragma unroll
        for (int nt = 0; nt < 16; ++nt) acc[nt] = (float4v){0.f, 0.f, 0.f, 0.f};
#pragma unroll
        for (int kt = 0; kt < 8; ++kt) {
#pragma unroll
            for (int nt = 0; nt < 16; ++nt) {
                const short8 b = *(const short8*)(wbb + (swzbase[kt] + nt * 8192));
                acc[nt] = __builtin_amdgcn_mfma_f32_16x16x32_bf16(
                    xfrag[kt], b, acc[nt], 0, 0, 0);
            }
        }

        // ---- epilogue: e = 2^(f*(1-2/(E+1))); D[word=q*4+r][hid=nt*16+c] ----
        float psum[4] = {0.f, 0.f, 0.f, 0.f};
#pragma unroll
        for (int nt = 0; nt < 16; ++nt) {
#pragma unroll
            for (int r = 0; r < 4; ++r) {
                const float y  = acc[nt][r] + bias16[nt];
                const float E  = __builtin_amdgcn_exp2f(y * 2.8853900817779268f);
                const float rd = __builtin_amdgcn_rcpf(E + 1.0f);
                const float t  = __builtin_fmaf(-2.0f, rd, 1.0f);   // tanh(y)
                const float e  = __builtin_amdgcn_exp2f(f216[nt] * t);
                acc[nt][r] = e;
                psum[r] += e;
            }
        }
        // ---- wave-local softmax denominators: DPP sum over the 16 c-lanes ----
        float rinv[4];
#pragma unroll
        for (int r = 0; r < 4; ++r)
            rinv[r] = __builtin_amdgcn_rcpf(row16_sum(psum[r]));

        // ---- final: out += x*e*rinv; x recovered in D-layout via identity MFMA
        const float4v zero4 = {0.f, 0.f, 0.f, 0.f};
#pragma unroll
        for (int nt = 0; nt < 16; ++nt) {
            float4v xD = __builtin_amdgcn_mfma_f32_16x16x32_bf16(
                xfrag[nt >> 1], ifr[nt & 1], zero4, 0, 0, 0);
#pragma unroll
            for (int r = 0; r < 4; ++r)
                oacc[nt] += xD[r] * (acc[nt][r] * rinv[r]);
        }
    }

    // ---- cross-q reduce (words are split across q-groups) + store ----
#pragma unroll
    for (int nt = 0; nt < 16; ++nt) {
        float v = oacc[nt];
        v += __shfl_xor(v, 16);
        v += __shfl_xor(v, 32);
        oacc[nt] = v;
    }
    if (q == 0) {
#pragma unroll
        for (int nt = 0; nt < 16; ++nt)
            out[(size_t)n * HID + nt * 16 + c] = oacc[nt];
    }
}

extern "C" void kernel_launch(void* const* d_in, const int* in_sizes, int n_in,
                              void* d_out, int out_size, void* d_ws, size_t ws_size,
                              hipStream_t stream) {
    const float* x    = (const float*)d_in[0];   // [2048, 64, 256] f32
    const float* W    = (const float*)d_in[1];   // [256, 256] f32
    const float* bias = (const float*)d_in[2];   // [256]
    const float* ctx  = (const float*)d_in[3];   // [256]
    (void)in_sizes; (void)n_in; (void)d_ws; (void)ws_size;

    attend_fused<<<GRID, 512, 0, stream>>>(x, W, bias, ctx, (float*)d_out);
}

// Round 6
// 372.563 us; speedup vs baseline: 1.2921x; 1.2921x over previous
//
#include <hip/hip_runtime.h>
#include <hip/hip_bf16.h>

#define HID 256
#define NROWS 2048
#define GRID (NROWS / 8)        // 256 blocks x 256 threads; 4 waves, 2 n-rows/wave

typedef __attribute__((ext_vector_type(8))) short short8;   // 8 bf16 (MFMA A/B frag)
typedef __attribute__((ext_vector_type(4))) float float4v;
typedef __attribute__((ext_vector_type(4))) unsigned int uint4v;

__device__ __forceinline__ unsigned int pk_bf16(float a, float b) {
    __hip_bfloat162 p = __float22bfloat162_rn(float2{a, b});  // v_cvt_pk_bf16_f32
    return *(unsigned int*)&p;
}

// sum across each 16-lane DPP row (VALU pipe, no LDS)
__device__ __forceinline__ float row16_sum(float v) {
    float t;
    t = __builtin_bit_cast(float, __builtin_amdgcn_update_dpp(
            0, __builtin_bit_cast(int, v), 0xB1, 0xf, 0xf, true));  // quad_perm(1,0,3,2)
    v += t;
    t = __builtin_bit_cast(float, __builtin_amdgcn_update_dpp(
            0, __builtin_bit_cast(int, v), 0x4E, 0xf, 0xf, true));  // quad_perm(2,3,0,1)
    v += t;
    t = __builtin_bit_cast(float, __builtin_amdgcn_update_dpp(
            0, __builtin_bit_cast(int, v), 0x124, 0xf, 0xf, true)); // row_ror:4
    v += t;
    t = __builtin_bit_cast(float, __builtin_amdgcn_update_dpp(
            0, __builtin_bit_cast(int, v), 0x128, 0xf, 0xf, true)); // row_ror:8
    v += t;
    return v;
}

// Wave-independent design (validated R4): W (bf16, XOR-swizzled, 128 KB) in LDS
// shared by all waves; each wave owns n-rows end-to-end so the softmax denom is
// wave-local (DPP) and the main loop has ZERO barriers. x for the final multiply
// is recovered in D-layout via identity-MFMA (no LDS staging of x).
// R5 fix: R4 spilled catastrophically (VGPR cap 256 split 128/128 by compiler;
// ~730 MB scratch traffic). Now 256-thread blocks -> 1 wave/SIMD -> 512-reg
// cap: demand ~220 fits, spill structurally impossible. Each wave runs 2 rows
// (8 chunk-iterations) so W is still staged once per block, one round per CU.
__global__ __launch_bounds__(256, 1) void attend_fused(
    const float* __restrict__ x, const float* __restrict__ W,
    const float* __restrict__ bias, const float* __restrict__ ctx,
    float* __restrict__ out)
{
    __shared__ unsigned short Wb[256 * 256];   // 128 KB, [col][k] bf16, swizzled

    const int tid  = threadIdx.x;
    const int wave = tid >> 6;    // 0..3
    const int lane = tid & 63;
    const int q    = lane >> 4;   // quad 0..3
    const int c    = lane & 15;
    const int nbase = blockIdx.x * 8 + wave * 2;      // this wave's first n-row
    const float* xw = x + (size_t)nbase * (64 * 256);

    // ---- issue chunk-0 x loads first: HBM stream starts under W staging ----
    // A-frag layout: lane (c,q) holds x[word c][k = kt*32 + q*8 + j]
    float4v xa[8], xb[8];
    {
        const float* xr = xw + c * 256 + q * 8;
#pragma unroll
        for (int kt = 0; kt < 8; ++kt) {
            xa[kt] = *(const float4v*)(xr + kt * 32);
            xb[kt] = *(const float4v*)(xr + kt * 32 + 4);
        }
    }

    // ---- stage W (f32 -> bf16) into swizzled LDS; W is L2/L3-resident ----
    {
        char* wbb = (char*)Wb;
#pragma unroll 4
        for (int i = 0; i < 64; ++i) {
            const int f4  = tid + 256 * i;        // 0..16383 float4 chunks
            const int col = f4 >> 6;              // W output-col (0..255)
            const int k4  = (f4 & 63) * 4;        // k position (floats)
            float4v v = *((const float4v*)W + f4);
            uint2 u;
            u.x = pk_bf16(v.x, v.y);
            u.y = pk_bf16(v.z, v.w);
            const int byte = (col * 512 + k4 * 2) ^ ((col & 7) << 4);  // T2 swizzle
            *(uint2*)(wbb + byte) = u;
        }
    }

    // ---- per-lane epilogue constants: hid col = nt*16 + c ----
    // e^(ctx*tanh(y)) = 2^(f*(1 - 2/(E+1))),  f = ctx*log2e,  E = 2^(2y*log2e)
    float bias16[16], f216[16];
#pragma unroll
    for (int nt = 0; nt < 16; ++nt) {
        const int o = nt * 16 + c;
        bias16[nt] = bias[o];
        f216[nt]  = ctx[o] * 1.4426950408889634f;
    }

    // ---- identity B-fragments: mfma(xfrag[kt'], ifr[p]) = x in D-layout ----
    // I[k][col] = 1 iff k == p*16 + col ; lane holds B[k=q*8+j][col=c]
    short8 ifr[2];
#pragma unroll
    for (int p = 0; p < 2; ++p) {
        short8 f = (short8){0, 0, 0, 0, 0, 0, 0, 0};
#pragma unroll
        for (int j = 0; j < 8; ++j)
            f[j] = (q * 8 + j == p * 16 + c) ? (short)0x3F80 : (short)0;
        ifr[p] = f;
    }

    // ---- loop-invariant swizzled read bases: XOR over FULL k-offset (R3 fix)
    int swzbase[8];
#pragma unroll
    for (int kt = 0; kt < 8; ++kt)
        swzbase[kt] = c * 512 + ((kt * 64 + q * 16) ^ ((c & 7) << 4));

    __syncthreads();   // the ONLY block barrier: Wb ready

    const char* wbb = (const char*)Wb;

    float oacc[16];
#pragma unroll
    for (int nt = 0; nt < 16; ++nt) oacc[nt] = 0.f;

#pragma unroll 1
    for (int m = 0; m < 8; ++m) {     // m = row*4 + chunk; 2 rows x 4 chunks
        // ---- cvt staged f32 -> bf16 A-frags (vmcnt wait for chunk m lands here)
        short8 xfrag[8];
#pragma unroll
        for (int kt = 0; kt < 8; ++kt) {
            uint4v u = { pk_bf16(xa[kt].x, xa[kt].y), pk_bf16(xa[kt].z, xa[kt].w),
                         pk_bf16(xb[kt].x, xb[kt].y), pk_bf16(xb[kt].z, xb[kt].w) };
            xfrag[kt] = __builtin_bit_cast(short8, u);
        }
        // ---- prefetch chunk m+1: in flight across GEMM+epilogue+final ----
        if (m < 7) {
            const int mn = m + 1;
            const float* xr = xw + (size_t)(mn >> 2) * (64 * 256)
                                 + ((mn & 3) * 16 + c) * 256 + q * 8;
#pragma unroll
            for (int kt = 0; kt < 8; ++kt) {
                xa[kt] = *(const float4v*)(xr + kt * 32);
                xb[kt] = *(const float4v*)(xr + kt * 32 + 4);
            }
        }

        // ---- GEMM: 16 words x 256 cols, B from swizzled LDS ----
        float4v acc[16];
#pragma unroll
        for (int nt = 0; nt < 16; ++nt) acc[nt] = (float4v){0.f, 0.f, 0.f, 0.f};
#pragma unroll
        for (int kt = 0; kt < 8; ++kt) {
#pragma unroll
            for (int nt = 0; nt < 16; ++nt) {
                const short8 b = *(const short8*)(wbb + (swzbase[kt] + nt * 8192));
                acc[nt] = __builtin_amdgcn_mfma_f32_16x16x32_bf16(
                    xfrag[kt], b, acc[nt], 0, 0, 0);
            }
        }

        // ---- epilogue: e = 2^(f*(1-2/(E+1))); D[word=q*4+r][hid=nt*16+c] ----
        float psum[4] = {0.f, 0.f, 0.f, 0.f};
#pragma unroll
        for (int nt = 0; nt < 16; ++nt) {
#pragma unroll
            for (int r = 0; r < 4; ++r) {
                const float y  = acc[nt][r] + bias16[nt];
                const float E  = __builtin_amdgcn_exp2f(y * 2.8853900817779268f);
                const float rd = __builtin_amdgcn_rcpf(E + 1.0f);
                const float t  = __builtin_fmaf(-2.0f, rd, 1.0f);   // tanh(y)
                const float e  = __builtin_amdgcn_exp2f(f216[nt] * t);
                acc[nt][r] = e;
                psum[r] += e;
            }
        }
        // ---- wave-local softmax denominators: DPP sum over the 16 c-lanes ----
        float rinv[4];
#pragma unroll
        for (int r = 0; r < 4; ++r)
            rinv[r] = __builtin_amdgcn_rcpf(row16_sum(psum[r]));

        // ---- final: out += x*e*rinv; x recovered in D-layout via identity MFMA
        const float4v zero4 = {0.f, 0.f, 0.f, 0.f};
#pragma unroll
        for (int nt = 0; nt < 16; ++nt) {
            float4v xD = __builtin_amdgcn_mfma_f32_16x16x32_bf16(
                xfrag[nt >> 1], ifr[nt & 1], zero4, 0, 0, 0);
#pragma unroll
            for (int r = 0; r < 4; ++r)
                oacc[nt] += xD[r] * (acc[nt][r] * rinv[r]);
        }

        // ---- row finished every 4 chunks: cross-q reduce + store + reset ----
        if ((m & 3) == 3) {
#pragma unroll
            for (int nt = 0; nt < 16; ++nt) {
                float v = oacc[nt];
                v += __shfl_xor(v, 16);
                v += __shfl_xor(v, 32);
                oacc[nt] = v;
            }
            if (q == 0) {
                const size_t n = (size_t)nbase + (m >> 2);
#pragma unroll
                for (int nt = 0; nt < 16; ++nt)
                    out[n * HID + nt * 16 + c] = oacc[nt];
            }
#pragma unroll
            for (int nt = 0; nt < 16; ++nt) oacc[nt] = 0.f;
        }
    }
}

extern "C" void kernel_launch(void* const* d_in, const int* in_sizes, int n_in,
                              void* d_out, int out_size, void* d_ws, size_t ws_size,
                              hipStream_t stream) {
    const float* x    = (const float*)d_in[0];   // [2048, 64, 256] f32
    const float* W    = (const float*)d_in[1];   // [256, 256] f32
    const float* bias = (const float*)d_in[2];   // [256]
    const float* ctx  = (const float*)d_in[3];   // [256]
    (void)in_sizes; (void)n_in; (void)d_ws; (void)ws_size;

    attend_fused<<<GRID, 256, 0, stream>>>(x, W, bias, ctx, (float*)d_out);
}

// Round 7
// 210.420 us; speedup vs baseline: 2.2877x; 1.7706x over previous
//
#include <hip/hip_runtime.h>
#include <hip/hip_bf16.h>

#define HID 256
#define NROWS 2048
#define NITER 8
#define GRID (NROWS / NITER)   // 256 persistent blocks = 1 per CU
#define PITCH 264              // bf16 row pitch: 256 + 8 pad
#define TILE_F (64 * 256)      // floats per row-tile (64 words x 256 hid)

typedef __attribute__((ext_vector_type(8))) short short8;   // 8 bf16 (MFMA A/B frag)
typedef __attribute__((ext_vector_type(4))) float float4v;
typedef __attribute__((ext_vector_type(4))) unsigned int uint4v;

__device__ __forceinline__ float bf2f(unsigned short u) {
    return __uint_as_float(((unsigned int)u) << 16);
}

__device__ __forceinline__ unsigned int pk_bf16(float a, float b) {
    __hip_bfloat162 p = __float22bfloat162_rn(float2{a, b});  // v_cvt_pk_bf16_f32
    return *(unsigned int*)&p;
}

// Raw barrier: drains LDS ops only (no vmcnt), so in-flight global loads for
// the next tile survive the barrier. sched_barrier brackets per rule 18.
__device__ __forceinline__ void bar_sync() {
    __builtin_amdgcn_sched_barrier(0);
    asm volatile("s_waitcnt lgkmcnt(0)");
    __builtin_amdgcn_s_barrier();
    __builtin_amdgcn_sched_barrier(0);
}

// sum across each 16-lane DPP row (VALU pipe, no LDS)
__device__ __forceinline__ float row16_sum(float v) {
    float t;
    t = __builtin_bit_cast(float, __builtin_amdgcn_update_dpp(
            0, __builtin_bit_cast(int, v), 0xB1, 0xf, 0xf, true));  // quad_perm(1,0,3,2)
    v += t;
    t = __builtin_bit_cast(float, __builtin_amdgcn_update_dpp(
            0, __builtin_bit_cast(int, v), 0x4E, 0xf, 0xf, true));  // quad_perm(2,3,0,1)
    v += t;
    t = __builtin_bit_cast(float, __builtin_amdgcn_update_dpp(
            0, __builtin_bit_cast(int, v), 0x124, 0xf, 0xf, true)); // row_ror:4
    v += t;
    t = __builtin_bit_cast(float, __builtin_amdgcn_update_dpp(
            0, __builtin_bit_cast(int, v), 0x128, 0xf, 0xf, true)); // row_ror:8
    v += t;
    return v;
}

// Persistent pipelined kernel, reg-staged deep prefetch (R1 structure, passed
// at 207.4 total). R7 change: __launch_bounds__(512,1) (was (512,2)). GRID=256
// is 1 block/CU anyway, so the old ",2" only capped VGPRs at 128 while demand
// is ~170 (bfrag 64 + R 32 + acc 32 + epilogue state) -> silent spill, the
// likely cause of the ~50us attend plateau (R4/R6 showed this harness's spill
// cost). ",1" lifts the cap to 256; 8 waves = 2/SIMD keep TLP.
__global__ __launch_bounds__(512, 1) void attend_fused(
    const float* __restrict__ x, const float* __restrict__ W,
    const float* __restrict__ bias, const float* __restrict__ ctx,
    float* __restrict__ out)
{
    __shared__ unsigned short xs[2][64 * PITCH];   // 66 KB double-buffered tile
    __shared__ float wsum[8][64];
    __shared__ float rinv[64];

    const int tid  = threadIdx.x;
    const int wave = tid >> 6;    // 0..7
    const int lane = tid & 63;
    const int q    = lane >> 4;   // quad 0..3
    const int c    = lane & 15;
    const int obase = wave * 32;  // wave's 32 output cols; lane pair: obase+2c+{0,1}
    const int n0 = blockIdx.x * NITER;

    // ---- issue tile-0 loads first so the HBM stream starts immediately ----
    float4v R[8];                 // 32 VGPR staging block (64 KB per block)
    {
        const float4v* xv = (const float4v*)(x + (size_t)n0 * TILE_F);
#pragma unroll
        for (int i = 0; i < 8; ++i) R[i] = xv[tid + 512 * i];
    }

    // ---- loop invariants (cover tile-0 latency): B frags straight from W ----
    // e^(c*tanh(y)) = 2^(f*(1 - 2/(E+1))),  f = c*log2e,  E = 2^(2y*log2e)
    float bb[2], f2[2];
    short8 bfrag[8][2];           // 64 VGPR: whole B tile for this wave
#pragma unroll
    for (int nt = 0; nt < 2; ++nt) {
        const int o = obase + 2 * c + nt;
        bb[nt] = bias[o];
        f2[nt] = ctx[o] * 1.4426950408889634f;
        const float* wr = W + (size_t)o * 256 + q * 8;
#pragma unroll
        for (int kt = 0; kt < 8; ++kt) {
            float4v w0 = *(const float4v*)(wr + kt * 32);
            float4v w1 = *(const float4v*)(wr + kt * 32 + 4);
            uint4v u = { pk_bf16(w0.x, w0.y), pk_bf16(w0.z, w0.w),
                         pk_bf16(w1.x, w1.y), pk_bf16(w1.z, w1.w) };
            bfrag[kt][nt] = __builtin_bit_cast(short8, u);
        }
    }

    // ---- cvt tile 0 -> xs[0]; issue tile-1 loads ----
#pragma unroll
    for (int i = 0; i < 8; ++i) {
        const int chunk = tid + 512 * i;
        const int r = chunk >> 6, col4 = (chunk & 63) * 4;
        uint2 u;
        u.x = pk_bf16(R[i].x, R[i].y);
        u.y = pk_bf16(R[i].z, R[i].w);
        *(uint2*)&xs[0][r * PITCH + col4] = u;
    }
    {
        const float4v* xv = (const float4v*)(x + (size_t)(n0 + 1) * TILE_F);
#pragma unroll
        for (int i = 0; i < 8; ++i) R[i] = xv[tid + 512 * i];
    }
    bar_sync();

    int cur = 0;
#pragma unroll 1
    for (int it = 0; it < NITER; ++it) {
        const unsigned short* xsc = xs[cur];

        // ---- GEMM: 64 rows x 32 cols per wave; zero vmem waits in here ----
        float4v acc[4][2];
#pragma unroll
        for (int mt = 0; mt < 4; ++mt)
#pragma unroll
            for (int nt = 0; nt < 2; ++nt)
                acc[mt][nt] = (float4v){0.f, 0.f, 0.f, 0.f};

#pragma unroll
        for (int kt = 0; kt < 8; ++kt) {
            short8 a[4];
#pragma unroll
            for (int mt = 0; mt < 4; ++mt)
                a[mt] = *(const short8*)&xsc[(mt * 16 + c) * PITCH + kt * 32 + q * 8];
#pragma unroll
            for (int nt = 0; nt < 2; ++nt)
#pragma unroll
                for (int mt = 0; mt < 4; ++mt)
                    acc[mt][nt] = __builtin_amdgcn_mfma_f32_16x16x32_bf16(
                        a[mt], bfrag[kt][nt], acc[mt][nt], 0, 0, 0);
        }

        // ---- epilogue: e = 2^(f*(1-2*rd)), rd = 1/(E+1); DPP row sums ----
        // D layout: row = 16*mt + 4*q + r, col = obase + 2*c + nt
        float psum[4][4];
#pragma unroll
        for (int mt = 0; mt < 4; ++mt)
#pragma unroll
            for (int r = 0; r < 4; ++r)
                psum[mt][r] = 0.f;

#pragma unroll
        for (int nt = 0; nt < 2; ++nt) {
#pragma unroll
            for (int mt = 0; mt < 4; ++mt) {
#pragma unroll
                for (int r = 0; r < 4; ++r) {
                    const float y  = acc[mt][nt][r] + bb[nt];
                    const float E  = __builtin_amdgcn_exp2f(y * 2.8853900817779268f);
                    const float rd = __builtin_amdgcn_rcpf(E + 1.0f);
                    const float t  = __builtin_fmaf(-2.0f, rd, 1.0f);   // = tanh(y)
                    const float e  = __builtin_amdgcn_exp2f(f2[nt] * t);
                    acc[mt][nt][r] = e;
                    psum[mt][r] += e;
                }
            }
        }
#pragma unroll
        for (int mt = 0; mt < 4; ++mt)
#pragma unroll
            for (int r = 0; r < 4; ++r)
                psum[mt][r] = row16_sum(psum[mt][r]);
        if (c == 0) {
#pragma unroll
            for (int mt = 0; mt < 4; ++mt) {
                float4v p = {psum[mt][0], psum[mt][1], psum[mt][2], psum[mt][3]};
                *(float4v*)&wsum[wave][mt * 16 + q * 4] = p;
            }
        }
        bar_sync();
        if (tid < 64) {
            const float t = wsum[0][tid] + wsum[1][tid] + wsum[2][tid] + wsum[3][tid]
                          + wsum[4][tid] + wsum[5][tid] + wsum[6][tid] + wsum[7][tid];
            rinv[tid] = __builtin_amdgcn_rcpf(t);
        }
        bar_sync();

        // ---- out[h] = sum_w x[w][h]*e[w][h]*rinv[w]; paired-col b32 reads ----
        float ri[4][4];
#pragma unroll
        for (int mt = 0; mt < 4; ++mt)
#pragma unroll
            for (int r = 0; r < 4; ++r)
                ri[mt][r] = rinv[mt * 16 + q * 4 + r];

        float outp[2] = {0.f, 0.f};
#pragma unroll
        for (int mt = 0; mt < 4; ++mt) {
#pragma unroll
            for (int r = 0; r < 4; ++r) {
                const int w = mt * 16 + q * 4 + r;
                unsigned int pair = *(const unsigned int*)&xsc[w * PITCH + obase + 2 * c];
                const float wgt = ri[mt][r];
                outp[0] += bf2f((unsigned short)pair)         * (acc[mt][0][r] * wgt);
                outp[1] += bf2f((unsigned short)(pair >> 16)) * (acc[mt][1][r] * wgt);
            }
        }
#pragma unroll
        for (int nt = 0; nt < 2; ++nt) {
            float v = outp[nt];
            v += __shfl_xor(v, 16);   // combine the 4 quads' disjoint w-ranges
            v += __shfl_xor(v, 32);
            outp[nt] = v;
        }
        if (q == 0)
            *(float2*)&out[(size_t)(n0 + it) * HID + obase + 2 * c] = float2{outp[0], outp[1]};

        // ---- stage tile it+1 (regs -> xs[cur^1]); issue loads for tile it+2.
        //      The vmcnt waits for R land here, covered by everything above. ----
        if (it + 1 < NITER) {
            unsigned short* xsn = (unsigned short*)xs[cur ^ 1];
#pragma unroll
            for (int i = 0; i < 8; ++i) {
                const int chunk = tid + 512 * i;
                const int r = chunk >> 6, col4 = (chunk & 63) * 4;
                uint2 u;
                u.x = pk_bf16(R[i].x, R[i].y);
                u.y = pk_bf16(R[i].z, R[i].w);
                *(uint2*)&xsn[r * PITCH + col4] = u;
            }
            if (it + 2 < NITER) {
                const float4v* xv = (const float4v*)(x + (size_t)(n0 + it + 2) * TILE_F);
#pragma unroll
                for (int i = 0; i < 8; ++i) R[i] = xv[tid + 512 * i];
            }
        }
        bar_sync();
        cur ^= 1;
    }
}

extern "C" void kernel_launch(void* const* d_in, const int* in_sizes, int n_in,
                              void* d_out, int out_size, void* d_ws, size_t ws_size,
                              hipStream_t stream) {
    const float* x    = (const float*)d_in[0];   // [2048, 64, 256] f32
    const float* W    = (const float*)d_in[1];   // [256, 256] f32
    const float* bias = (const float*)d_in[2];   // [256]
    const float* ctx  = (const float*)d_in[3];   // [256]
    (void)in_sizes; (void)n_in; (void)d_ws; (void)ws_size;

    attend_fused<<<GRID, 512, 0, stream>>>(x, W, bias, ctx, (float*)d_out);
}